// Round 12
// baseline (172.540 us; speedup 1.0000x reference)
//
#include <hip/hip_runtime.h>

// out[t][i][j] = sum_k x[i][k]*W[j][k] + bias[j] + sum_r low[t][i][r]*Bm[ti][j][r]
// low[t][i][r] = sum_k x[i][k]*A[ti][r][k]
// Base GEMM in single-stream fp16 MFMA. v9:
//  - lora_main PERSISTENT T=2: each block does two 128x128 tiles (same bm,
//    bn and bn+4). Tile-1's nt-stores drain through L2->HBM while tile-2's
//    K-loop computes -> write/compute overlap inside every CU (r9/r11 showed
//    the write burst, not the K-loop schedule, is the wall).
//  - wave shape back to r9's 64x64 acc (4 waves, 2x2), 32KB LDS, vmcnt(4).
//  - lora_low unchanged from round 11 (isolate one variable).

typedef __attribute__((ext_vector_type(8))) _Float16 f16x8;
typedef __attribute__((ext_vector_type(4))) float f32x4;
typedef __attribute__((ext_vector_type(4))) unsigned short us4;
typedef __attribute__((ext_vector_type(8))) unsigned short us8;

namespace {
constexpr int kM = 16384, kDin = 1024, kDout = 1024, kR = 16, kT = 4;
constexpr size_t OFF_XF  = 0;               // [16384][1024] fp16 = 32 MiB
constexpr size_t OFF_WF  = 33554432;        // [1024][1024] fp16 = 2 MiB
constexpr size_t OFF_LOW = 35651584;        // [4][16384][16] fp16 = 2 MiB
}

__device__ inline unsigned short f2h(float f) {
  _Float16 h = (_Float16)f;  // RNE
  return __builtin_bit_cast(unsigned short, h);
}
__device__ inline void gload_lds16(const void* g, void* l) {
  __builtin_amdgcn_global_load_lds(
      (const __attribute__((address_space(1))) unsigned int*)g,
      (__attribute__((address_space(3))) unsigned int*)l, 16, 0, 0);
}
__device__ inline f32x4 mfma_f16(f16x8 a, f16x8 b, f32x4 c) {
  return __builtin_amdgcn_mfma_f32_16x16x32_f16(a, b, c, 0, 0, 0);
}

// ---------------------------------------------------------------------------
// Kernel 1: W fp32->fp16 prelude + low[t][i][r] = x[i].A[ti][r] (+ xf = fp16(x))
// (unchanged from round 11)
// ---------------------------------------------------------------------------
__global__ __launch_bounds__(256) void lora_low(const float* __restrict__ x,
                                                const float* __restrict__ W,
                                                const float* __restrict__ A,
                                                const int* __restrict__ tuner,
                                                unsigned short* __restrict__ lowb,
                                                unsigned short* __restrict__ xf,
                                                unsigned short* __restrict__ wf) {
  {
    const int idx = blockIdx.x * 256 + threadIdx.x;
#pragma unroll
    for (int p = 0; p < 2; ++p) {
      const int j = idx + p * 131072;
      const float4 v = ((const float4*)W)[j];
      us4 h;
      h[0] = f2h(v.x); h[1] = f2h(v.y); h[2] = f2h(v.z); h[3] = f2h(v.w);
      ((us4*)wf)[j] = h;
    }
  }

  __shared__ float xs[64][34];  // [k][row]
  __shared__ float as[64][68];  // [k][t*16+r] (16B-aligned rows)
  const int tid = threadIdx.x;
  const int i0  = blockIdx.x * 32;
  const int tx  = tid & 15;
  const int ty  = tid >> 4;
  float acc[2][4] = {{0.f, 0.f, 0.f, 0.f}, {0.f, 0.f, 0.f, 0.f}};

  for (int kt = 0; kt < kDin; kt += 64) {
    __syncthreads();
#pragma unroll
    for (int p = 0; p < 2; ++p) {  // x tile: 32 rows x 64 k (+ fused xf store)
      const int f = tid + p * 256;
      const int row = f >> 4, kq = (f & 15) * 4;
      const float4 v = *(const float4*)(x + (size_t)(i0 + row) * kDin + kt + kq);
      xs[kq + 0][row] = v.x; xs[kq + 1][row] = v.y;
      xs[kq + 2][row] = v.z; xs[kq + 3][row] = v.w;
      us4 h;
      h[0] = f2h(v.x); h[1] = f2h(v.y); h[2] = f2h(v.z); h[3] = f2h(v.w);
      *(us4*)(xf + (size_t)(i0 + row) * kDin + kt + kq) = h;
    }
#pragma unroll
    for (int p = 0; p < 4; ++p) {  // A tile: 64 (t,r) rows x 64 k
      const int f = tid + p * 256;
      const int ar = f >> 4, kq = (f & 15) * 4;
      const int ti = tuner[ar >> 4];
      const float4 v = *(const float4*)(A + ((size_t)ti * kR + (ar & 15)) * kDin + kt + kq);
      as[kq + 0][ar] = v.x; as[kq + 1][ar] = v.y;
      as[kq + 2][ar] = v.z; as[kq + 3][ar] = v.w;
    }
    __syncthreads();
#pragma unroll 4
    for (int k = 0; k < 64; ++k) {
      const float2 xv = *(const float2*)&xs[k][ty * 2];      // b64
      const float4 av = *(const float4*)&as[k][tx * 4];      // b128
      acc[0][0] += xv.x * av.x; acc[0][1] += xv.x * av.y;
      acc[0][2] += xv.x * av.z; acc[0][3] += xv.x * av.w;
      acc[1][0] += xv.y * av.x; acc[1][1] += xv.y * av.y;
      acc[1][2] += xv.y * av.z; acc[1][3] += xv.y * av.w;
    }
  }
#pragma unroll
  for (int ii = 0; ii < 2; ++ii) {
    us4 o;
#pragma unroll
    for (int j = 0; j < 4; ++j) o[j] = f2h(acc[ii][j]);
    *(us4*)(lowb + ((size_t)(tx >> 2) * kM + i0 + ty * 2 + ii) * kR + (tx & 3) * 4) = o;
  }
}

// ---------------------------------------------------------------------------
// Kernel 2: persistent 2-tile fp16 MFMA GEMM. Per tile: 128x128 (BK=32),
// 4 waves (2x2, wave 64x64, acc[4][4]); counted-vmcnt dbuf; XOR swizzle
// both-sides; swapped-operand MFMA -> f32x4 nt-stores; rank-16 K-extension
// epilogue. LDS 2 x 16KB. Tile pair: (bm, bn) then (bm, bn+4).
// ---------------------------------------------------------------------------
__global__ __launch_bounds__(256, 2) void lora_main(
    const unsigned short* __restrict__ xf, const unsigned short* __restrict__ wf,
    const float* __restrict__ bias, const float* __restrict__ Bm,
    const int* __restrict__ tuner, const unsigned short* __restrict__ lowb,
    float* __restrict__ out) {
  __shared__ __align__(16) unsigned char smem[32768];
  const int tid  = threadIdx.x;
  const int lane = tid & 63;
  const int w    = tid >> 6;

  // XCD swizzle (512 blocks, %8==0 -> bijective)
  const int swz = ((int)blockIdx.x & 7) * 64 + ((int)blockIdx.x >> 3);
  const int bm = swz >> 2, bn2 = swz & 3;
  const size_t i0 = (size_t)bm * 128;
  const int wm = w >> 1, wn = w & 1;   // wave tile: rows wm*64, cols wn*64

  const int chsw = ((lane & 3) ^ ((lane >> 3) & 3)) * 8;
  const int kg = lane >> 4;
  const int rl = lane & 15;
  const int csw = kg ^ ((rl >> 1) & 3);
  const int rdA = (wm * 64 + rl) * 64 + csw * 16;          // A region [0,8K)
  const int rdB = 8192 + (wn * 64 + rl) * 64 + csw * 16;   // B region [8K,16K)

#pragma unroll 1
  for (int tt = 0; tt < 2; ++tt) {
    const size_t j0 = (size_t)(bn2 + 4 * tt) * 128;

    // staging sources: 16 chunks (1KB = 16 rows x 64B); wave w -> c = 4w+q
    const unsigned short* gsrc_q[4];
    int ldsoff_q[4];
#pragma unroll
    for (int q = 0; q < 4; ++q) {
      const int c = 4 * w + q;
      const bool isA = c < 8;
      const size_t rowb = (isA ? i0 + c * 16 : j0 + (c - 8) * 16) + (lane >> 2);
      gsrc_q[q] = (isA ? xf : wf) + rowb * kDin + chsw;
      ldsoff_q[q] = c * 1024;   // A: [0,8K); B: [8K,16K)
    }

    f32x4 acc[4][4];   // acc[n][m] = out^T fragments
#pragma unroll
    for (int n = 0; n < 4; ++n)
#pragma unroll
      for (int m = 0; m < 4; ++m) acc[n][m] = (f32x4){0.f, 0.f, 0.f, 0.f};

    auto compute_step = [&](const unsigned char* B0) {
      f16x8 a[4], b[4];
#pragma unroll
      for (int m = 0; m < 4; ++m) a[m] = *(const f16x8*)(B0 + rdA + m * 1024);
#pragma unroll
      for (int n = 0; n < 4; ++n) b[n] = *(const f16x8*)(B0 + rdB + n * 1024);
      __builtin_amdgcn_s_setprio(1);
#pragma unroll
      for (int n = 0; n < 4; ++n)
#pragma unroll
        for (int m = 0; m < 4; ++m)
          acc[n][m] = mfma_f16(b[n], a[m], acc[n][m]);  // swapped: W as A-op
      __builtin_amdgcn_s_setprio(0);
    };

    // prologue: stage K-step 0 into buf0 (4 loads/wave; tile-1 stores may
    // still be draining — vmcnt waits below include them, partial overlap)
#pragma unroll
    for (int q = 0; q < 4; ++q)
      gload_lds16(gsrc_q[q], smem + ldsoff_q[q]);

    for (int s = 0; s < 31; ++s) {
      const int p = s & 1;
      {  // prefetch step s+1 into buf p^1
        unsigned char* dst = smem + (p ^ 1) * 16384;
        const int ko = (s + 1) * 32;
#pragma unroll
        for (int q = 0; q < 4; ++q)
          gload_lds16(gsrc_q[q] + ko, dst + ldsoff_q[q]);
      }
      asm volatile("s_waitcnt vmcnt(4)" ::: "memory");  // step-s loads landed
      __builtin_amdgcn_s_barrier();
      asm volatile("" ::: "memory");
      compute_step(smem + p * 16384);
      asm volatile("s_waitcnt lgkmcnt(0)" ::: "memory");
      __builtin_amdgcn_s_barrier();
      asm volatile("" ::: "memory");
    }
    asm volatile("s_waitcnt vmcnt(0)" ::: "memory");
    __builtin_amdgcn_s_barrier();
    asm volatile("" ::: "memory");
    compute_step(smem + 16384);   // peeled step 31 reads buf1

    // bias: lane's 4 consecutive out cols = j0 + wn*64 + n*16 + kg*4 + {0..3}
#pragma unroll
    for (int n = 0; n < 4; ++n) {
      const f32x4 bv = *(const f32x4*)(bias + j0 + wn * 64 + n * 16 + kg * 4);
#pragma unroll
      for (int m = 0; m < 4; ++m)
#pragma unroll
        for (int r = 0; r < 4; ++r) acc[n][m][r] += bv[r];
    }

    // Epilogue tiles in buf0 [0,16K): Lt [kg4][128][16B] at [0,8K),
    // Mt [kg4][128][16B] at [8K,16K). Zero kg2-3 pads ([4K,8K) and [12K,16K)).
    // (buf0's last K-loop reads ended at step 30's barrier; step 31 read buf1.)
    {
      const us8 z = {0, 0, 0, 0, 0, 0, 0, 0};
      unsigned char* p = (tid < 128) ? (smem + 4096 + tid * 32)
                                     : (smem + 12288 + (tid - 128) * 32);
      *(us8*)p = z;
      *(us8*)(p + 16) = z;
    }

    for (int t = 0; t < kT; ++t) {
      __syncthreads();  // pads visible / previous t's reads done
      {
        const int row = tid >> 1, half = tid & 1;
        // Lt (low tile, fp16): 128 rows (same i0 both tiles)
        const us8 lv = *(const us8*)(lowb + ((size_t)t * kM + i0 + row) * kR + half * 8);
        *(us8*)(smem + half * 2048 + row * 16) = lv;
        // Mt (Bm tile, fp32->fp16): 128 rows
        const int ti = tuner[t];
        const float* bp = Bm + ((size_t)ti * kDout + j0 + row) * kR + half * 8;
        const float4 m0 = *(const float4*)bp;
        const float4 m1 = *(const float4*)(bp + 4);
        us8 mv;
        mv[0] = f2h(m0.x); mv[1] = f2h(m0.y); mv[2] = f2h(m0.z); mv[3] = f2h(m0.w);
        mv[4] = f2h(m1.x); mv[5] = f2h(m1.y); mv[6] = f2h(m1.z); mv[7] = f2h(m1.w);
        *(us8*)(smem + 8192 + half * 2048 + row * 16) = mv;
      }
      __syncthreads();

      f16x8 lf[4], mf[4];
#pragma unroll
      for (int m = 0; m < 4; ++m)
        lf[m] = *(const f16x8*)(smem + kg * 2048 + (wm * 64 + m * 16 + rl) * 16);
#pragma unroll
      for (int n = 0; n < 4; ++n)
        mf[n] = *(const f16x8*)(smem + 8192 + kg * 2048 + (wn * 64 + n * 16 + rl) * 16);

#pragma unroll
      for (int n = 0; n < 4; ++n)
#pragma unroll
        for (int m = 0; m < 4; ++m) {
          const f32x4 d = mfma_f16(mf[n], lf[m], acc[n][m]);  // = out^T frag
          const size_t row = (size_t)t * kM + i0 + wm * 64 + m * 16 + rl;
          const int    col = (int)j0 + wn * 64 + n * 16 + kg * 4;
          __builtin_nontemporal_store(d, (f32x4*)(out + row * kDout + col));
        }
    }
    __syncthreads();  // last t's LDS reads done before next tile re-stages
  }
}

// ---------------------------------------------------------------------------
extern "C" void kernel_launch(void* const* d_in, const int* in_sizes, int n_in,
                              void* d_out, int out_size, void* d_ws, size_t ws_size,
                              hipStream_t stream) {
  const float* x    = (const float*)d_in[0];
  const float* W    = (const float*)d_in[1];
  const float* bias = (const float*)d_in[2];
  const float* lA   = (const float*)d_in[3];
  const float* lB   = (const float*)d_in[4];
  const int*   ti   = (const int*)d_in[5];
  float* out = (float*)d_out;

  unsigned char* ws = (unsigned char*)d_ws;
  unsigned short* xfp  = (unsigned short*)(ws + OFF_XF);
  unsigned short* wfp  = (unsigned short*)(ws + OFF_WF);
  unsigned short* lowb = (unsigned short*)(ws + OFF_LOW);

  lora_low<<<kM / 32, 256, 0, stream>>>(x, W, lA, ti, lowb, xfp, wfp);
  lora_main<<<512, 256, 0, stream>>>(xfp, wfp, bias, lB, ti, lowb, out);
}

// Round 13
// 157.383 us; speedup vs baseline: 1.0963x; 1.0963x over previous
//
#include <hip/hip_runtime.h>

// out[t][i][j] = sum_k x[i][k]*W[j][k] + bias[j] + sum_r low[t][i][r]*Bm[ti][j][r]
// low[t][i][r] = sum_k x[i][k]*A[ti][r][k]
// Base GEMM in single-stream fp16 MFMA. v10 (r11 base + barrier-free epilogue):
//  - lora_main K-loop identical to r11 (tile 128x256, 4 waves of 64x128,
//    grid 512, counted-vmcnt dbuf, both-sides XOR swizzle, swapped-operand
//    MFMA -> f32x4 nt-stores).
//  - epilogue: NO LDS, NO barriers. Fragments loaded directly from global:
//    lf = 16B of lowb[t][row][kg*8..] (kg<2, else 0); mf = 16B of pre-
//    converted Bmf[ti][col][kg*8..]. Same bytes the LDS path staged ->
//    bit-identical results; stores of t overlap loads of t+1 freely.
//  - lora_low prelude additionally converts lora_B -> fp16 Bmf (1 float4/thr).

typedef __attribute__((ext_vector_type(8))) _Float16 f16x8;
typedef __attribute__((ext_vector_type(4))) float f32x4;
typedef __attribute__((ext_vector_type(4))) unsigned short us4;
typedef __attribute__((ext_vector_type(8))) unsigned short us8;

namespace {
constexpr int kM = 16384, kDin = 1024, kDout = 1024, kR = 16, kT = 4;
constexpr size_t OFF_XF  = 0;               // [16384][1024] fp16 = 32 MiB
constexpr size_t OFF_WF  = 33554432;        // [1024][1024] fp16 = 2 MiB
constexpr size_t OFF_LOW = 35651584;        // [4][16384][16] fp16 = 2 MiB
constexpr size_t OFF_BMF = 37748736;        // [8][1024][16] fp16 = 256 KiB
}

__device__ inline unsigned short f2h(float f) {
  _Float16 h = (_Float16)f;  // RNE
  return __builtin_bit_cast(unsigned short, h);
}
__device__ inline void gload_lds16(const void* g, void* l) {
  __builtin_amdgcn_global_load_lds(
      (const __attribute__((address_space(1))) unsigned int*)g,
      (__attribute__((address_space(3))) unsigned int*)l, 16, 0, 0);
}
__device__ inline f32x4 mfma_f16(f16x8 a, f16x8 b, f32x4 c) {
  return __builtin_amdgcn_mfma_f32_16x16x32_f16(a, b, c, 0, 0, 0);
}

// ---------------------------------------------------------------------------
// Kernel 1: preludes (W->fp16, lora_B->fp16) + low[t][i][r] = x[i].A[ti][r]
// (+ xf = fp16(x)).  Main body unchanged from round 11.
// ---------------------------------------------------------------------------
__global__ __launch_bounds__(256) void lora_low(const float* __restrict__ x,
                                                const float* __restrict__ W,
                                                const float* __restrict__ A,
                                                const float* __restrict__ Bm,
                                                const int* __restrict__ tuner,
                                                unsigned short* __restrict__ lowb,
                                                unsigned short* __restrict__ xf,
                                                unsigned short* __restrict__ wf,
                                                unsigned short* __restrict__ bmf) {
  {
    const int idx = blockIdx.x * 256 + threadIdx.x;
#pragma unroll
    for (int p = 0; p < 2; ++p) {  // W: 262144 float4
      const int j = idx + p * 131072;
      const float4 v = ((const float4*)W)[j];
      us4 h;
      h[0] = f2h(v.x); h[1] = f2h(v.y); h[2] = f2h(v.z); h[3] = f2h(v.w);
      ((us4*)wf)[j] = h;
    }
    if (idx < 32768) {             // lora_B: 8*1024*16 fp32 = 32768 float4
      const float4 v = ((const float4*)Bm)[idx];
      us4 h;
      h[0] = f2h(v.x); h[1] = f2h(v.y); h[2] = f2h(v.z); h[3] = f2h(v.w);
      ((us4*)bmf)[idx] = h;
    }
  }

  __shared__ float xs[64][34];  // [k][row]
  __shared__ float as[64][68];  // [k][t*16+r] (16B-aligned rows)
  const int tid = threadIdx.x;
  const int i0  = blockIdx.x * 32;
  const int tx  = tid & 15;
  const int ty  = tid >> 4;
  float acc[2][4] = {{0.f, 0.f, 0.f, 0.f}, {0.f, 0.f, 0.f, 0.f}};

  for (int kt = 0; kt < kDin; kt += 64) {
    __syncthreads();
#pragma unroll
    for (int p = 0; p < 2; ++p) {  // x tile: 32 rows x 64 k (+ fused xf store)
      const int f = tid + p * 256;
      const int row = f >> 4, kq = (f & 15) * 4;
      const float4 v = *(const float4*)(x + (size_t)(i0 + row) * kDin + kt + kq);
      xs[kq + 0][row] = v.x; xs[kq + 1][row] = v.y;
      xs[kq + 2][row] = v.z; xs[kq + 3][row] = v.w;
      us4 h;
      h[0] = f2h(v.x); h[1] = f2h(v.y); h[2] = f2h(v.z); h[3] = f2h(v.w);
      *(us4*)(xf + (size_t)(i0 + row) * kDin + kt + kq) = h;
    }
#pragma unroll
    for (int p = 0; p < 4; ++p) {  // A tile: 64 (t,r) rows x 64 k
      const int f = tid + p * 256;
      const int ar = f >> 4, kq = (f & 15) * 4;
      const int ti = tuner[ar >> 4];
      const float4 v = *(const float4*)(A + ((size_t)ti * kR + (ar & 15)) * kDin + kt + kq);
      as[kq + 0][ar] = v.x; as[kq + 1][ar] = v.y;
      as[kq + 2][ar] = v.z; as[kq + 3][ar] = v.w;
    }
    __syncthreads();
#pragma unroll 4
    for (int k = 0; k < 64; ++k) {
      const float2 xv = *(const float2*)&xs[k][ty * 2];      // b64
      const float4 av = *(const float4*)&as[k][tx * 4];      // b128
      acc[0][0] += xv.x * av.x; acc[0][1] += xv.x * av.y;
      acc[0][2] += xv.x * av.z; acc[0][3] += xv.x * av.w;
      acc[1][0] += xv.y * av.x; acc[1][1] += xv.y * av.y;
      acc[1][2] += xv.y * av.z; acc[1][3] += xv.y * av.w;
    }
  }
#pragma unroll
  for (int ii = 0; ii < 2; ++ii) {
    us4 o;
#pragma unroll
    for (int j = 0; j < 4; ++j) o[j] = f2h(acc[ii][j]);
    *(us4*)(lowb + ((size_t)(tx >> 2) * kM + i0 + ty * 2 + ii) * kR + (tx & 3) * 4) = o;
  }
}

// ---------------------------------------------------------------------------
// Kernel 2: main fp16 MFMA GEMM, tile 128x256 (BK=32), 256 thr = 4 waves as
// 2m x 2n (wave 64x128, acc[8][4]); grid 512. K-loop identical to round 11.
// Epilogue: barrier-free, LDS-free (direct global fragment loads).
// ---------------------------------------------------------------------------
__global__ __launch_bounds__(256, 2) void lora_main(
    const unsigned short* __restrict__ xf, const unsigned short* __restrict__ wf,
    const float* __restrict__ bias, const unsigned short* __restrict__ bmf,
    const int* __restrict__ tuner, const unsigned short* __restrict__ lowb,
    float* __restrict__ out) {
  __shared__ __align__(16) unsigned char smem[49152];
  const int tid  = threadIdx.x;
  const int lane = tid & 63;
  const int w    = tid >> 6;

  // XCD swizzle (512 blocks, %8==0 -> bijective)
  const int swz = ((int)blockIdx.x & 7) * 64 + ((int)blockIdx.x >> 3);
  const int bm = swz >> 2, bn = swz & 3;
  const size_t i0 = (size_t)bm * 128, j0 = (size_t)bn * 256;
  const int wm = w >> 1, wn = w & 1;   // wave tile: rows wm*64, cols wn*128

  // staging: 24 chunks (1KB = 16 rows x 64B); wave w stages c = 6w..6w+5
  const int chsw = ((lane & 3) ^ ((lane >> 3) & 3)) * 8;
  const unsigned short* gsrc_q[6];
  int ldsoff_q[6];
#pragma unroll
  for (int q = 0; q < 6; ++q) {
    const int c = 6 * w + q;
    const bool isA = c < 8;
    const size_t rowb = (isA ? i0 + c * 16 : j0 + (c - 8) * 16) + (lane >> 2);
    gsrc_q[q] = (isA ? xf : wf) + rowb * kDin + chsw;
    ldsoff_q[q] = c * 1024;   // A: [0,8K); B: [8K,24K)
  }

  f32x4 acc[8][4];   // acc[n][m] = out^T fragments
#pragma unroll
  for (int n = 0; n < 8; ++n)
#pragma unroll
    for (int m = 0; m < 4; ++m) acc[n][m] = (f32x4){0.f, 0.f, 0.f, 0.f};

  const int kg = lane >> 4;
  const int rl = lane & 15;
  const int csw = kg ^ ((rl >> 1) & 3);
  const int rdA = (wm * 64 + rl) * 64 + csw * 16;           // A region [0,8K)
  const int rdB = 8192 + (wn * 128 + rl) * 64 + csw * 16;   // B region [8K,24K)

  auto compute_step = [&](const unsigned char* B0) {
    f16x8 a[4], b[8];
#pragma unroll
    for (int m = 0; m < 4; ++m) a[m] = *(const f16x8*)(B0 + rdA + m * 1024);
#pragma unroll
    for (int n = 0; n < 8; ++n) b[n] = *(const f16x8*)(B0 + rdB + n * 1024);
    __builtin_amdgcn_s_setprio(1);
#pragma unroll
    for (int n = 0; n < 8; ++n)
#pragma unroll
      for (int m = 0; m < 4; ++m)
        acc[n][m] = mfma_f16(b[n], a[m], acc[n][m]);   // swapped: W as A-operand
    __builtin_amdgcn_s_setprio(0);
  };

  // prologue: stage K-step 0 into buf0 (6 loads/wave)
#pragma unroll
  for (int q = 0; q < 6; ++q)
    gload_lds16(gsrc_q[q], smem + ldsoff_q[q]);

  for (int s = 0; s < 31; ++s) {
    const int p = s & 1;
    {  // prefetch step s+1 into buf p^1 (12 loads/wave outstanding)
      unsigned char* dst = smem + (p ^ 1) * 24576;
      const int ko = (s + 1) * 32;
#pragma unroll
      for (int q = 0; q < 6; ++q)
        gload_lds16(gsrc_q[q] + ko, dst + ldsoff_q[q]);
    }
    asm volatile("s_waitcnt vmcnt(6)" ::: "memory");  // step-s loads landed
    __builtin_amdgcn_s_barrier();
    asm volatile("" ::: "memory");
    compute_step(smem + p * 24576);
    asm volatile("s_waitcnt lgkmcnt(0)" ::: "memory");
    __builtin_amdgcn_s_barrier();
    asm volatile("" ::: "memory");
  }
  asm volatile("s_waitcnt vmcnt(0)" ::: "memory");
  __builtin_amdgcn_s_barrier();
  asm volatile("" ::: "memory");
  compute_step(smem + 24576);   // peeled step 31 reads buf1

  // bias: lane's 4 consecutive out cols = j0 + wn*128 + n*16 + kg*4 + {0..3}
#pragma unroll
  for (int n = 0; n < 8; ++n) {
    const f32x4 bv = *(const f32x4*)(bias + j0 + wn * 128 + n * 16 + kg * 4);
#pragma unroll
    for (int m = 0; m < 4; ++m)
#pragma unroll
      for (int r = 0; r < 4; ++r) acc[n][m][r] += bv[r];
  }

  // -------- barrier-free epilogue: direct global fragment loads ----------
  // A/B-operand layout for 16x16x32: lane l holds elems k = (l>>4)*8 + j.
  // kg<2 -> 16B of real data (r = kg*8..kg*8+7); kg>=2 -> zeros (K pad).
  const f16x8 zf = {};
  for (int t = 0; t < kT; ++t) {
    const int ti = tuner[t];
    const unsigned short* lrow = lowb + (size_t)t * kM * kR;
    const unsigned short* mrow = bmf + (size_t)ti * kDout * kR;

    f16x8 lf[4], mf[8];
#pragma unroll
    for (int m = 0; m < 4; ++m) {
      lf[m] = zf;
      if (kg < 2)
        lf[m] = *(const f16x8*)(lrow + (i0 + wm * 64 + m * 16 + rl) * kR + kg * 8);
    }
#pragma unroll
    for (int n = 0; n < 8; ++n) {
      mf[n] = zf;
      if (kg < 2)
        mf[n] = *(const f16x8*)(mrow + (j0 + wn * 128 + n * 16 + rl) * kR + kg * 8);
    }

#pragma unroll
    for (int n = 0; n < 8; ++n)
#pragma unroll
      for (int m = 0; m < 4; ++m) {
        const f32x4 d = mfma_f16(mf[n], lf[m], acc[n][m]);  // = out^T fragment
        const size_t row = (size_t)t * kM + i0 + wm * 64 + m * 16 + rl;
        const int    col = (int)j0 + wn * 128 + n * 16 + kg * 4;
        __builtin_nontemporal_store(d, (f32x4*)(out + row * kDout + col));
      }
  }
}

// ---------------------------------------------------------------------------
extern "C" void kernel_launch(void* const* d_in, const int* in_sizes, int n_in,
                              void* d_out, int out_size, void* d_ws, size_t ws_size,
                              hipStream_t stream) {
  const float* x    = (const float*)d_in[0];
  const float* W    = (const float*)d_in[1];
  const float* bias = (const float*)d_in[2];
  const float* lA   = (const float*)d_in[3];
  const float* lB   = (const float*)d_in[4];
  const int*   ti   = (const int*)d_in[5];
  float* out = (float*)d_out;

  unsigned char* ws = (unsigned char*)d_ws;
  unsigned short* xfp  = (unsigned short*)(ws + OFF_XF);
  unsigned short* wfp  = (unsigned short*)(ws + OFF_WF);
  unsigned short* lowb = (unsigned short*)(ws + OFF_LOW);
  unsigned short* bmfp = (unsigned short*)(ws + OFF_BMF);

  lora_low<<<kM / 32, 256, 0, stream>>>(x, W, lA, lB, ti, lowb, xfp, wfp, bmfp);
  lora_main<<<512, 256, 0, stream>>>(xfp, wfp, bias, bmfp, ti, lowb, out);
}

// Round 16
// 142.043 us; speedup vs baseline: 1.2147x; 1.1080x over previous
//
#include <hip/hip_runtime.h>

// out[t][i][j] = sum_k x[i][k]*W[j][k] + bias[j] + sum_r low[t][i][r]*Bm[ti][j][r]
// low[t][i][r] = sum_k x[i][k]*A[ti][r][k]
// Base GEMM in single-stream fp16 MFMA. v11 = r11 EXACTLY, minus nt-stores
// (single-variable probe: nt bypasses L2 -> kernel-end drain waits on HBM;
// plain stores retire at L2 and the writeback overlaps subsequent work).

typedef __attribute__((ext_vector_type(8))) _Float16 f16x8;
typedef __attribute__((ext_vector_type(4))) float f32x4;
typedef __attribute__((ext_vector_type(4))) unsigned short us4;
typedef __attribute__((ext_vector_type(8))) unsigned short us8;

namespace {
constexpr int kM = 16384, kDin = 1024, kDout = 1024, kR = 16, kT = 4;
constexpr size_t OFF_XF  = 0;               // [16384][1024] fp16 = 32 MiB
constexpr size_t OFF_WF  = 33554432;        // [1024][1024] fp16 = 2 MiB
constexpr size_t OFF_LOW = 35651584;        // [4][16384][16] fp16 = 2 MiB
}

__device__ inline unsigned short f2h(float f) {
  _Float16 h = (_Float16)f;  // RNE
  return __builtin_bit_cast(unsigned short, h);
}
__device__ inline void gload_lds16(const void* g, void* l) {
  __builtin_amdgcn_global_load_lds(
      (const __attribute__((address_space(1))) unsigned int*)g,
      (__attribute__((address_space(3))) unsigned int*)l, 16, 0, 0);
}
__device__ inline f32x4 mfma_f16(f16x8 a, f16x8 b, f32x4 c) {
  return __builtin_amdgcn_mfma_f32_16x16x32_f16(a, b, c, 0, 0, 0);
}

// ---------------------------------------------------------------------------
// Kernel 1: W fp32->fp16 prelude + low[t][i][r] = x[i].A[ti][r] (+ xf = fp16(x))
// (unchanged from round 11)
// ---------------------------------------------------------------------------
__global__ __launch_bounds__(256) void lora_low(const float* __restrict__ x,
                                                const float* __restrict__ W,
                                                const float* __restrict__ A,
                                                const int* __restrict__ tuner,
                                                unsigned short* __restrict__ lowb,
                                                unsigned short* __restrict__ xf,
                                                unsigned short* __restrict__ wf) {
  {
    const int idx = blockIdx.x * 256 + threadIdx.x;
#pragma unroll
    for (int p = 0; p < 2; ++p) {
      const int j = idx + p * 131072;
      const float4 v = ((const float4*)W)[j];
      us4 h;
      h[0] = f2h(v.x); h[1] = f2h(v.y); h[2] = f2h(v.z); h[3] = f2h(v.w);
      ((us4*)wf)[j] = h;
    }
  }

  __shared__ float xs[64][34];  // [k][row]
  __shared__ float as[64][68];  // [k][t*16+r] (16B-aligned rows)
  const int tid = threadIdx.x;
  const int i0  = blockIdx.x * 32;
  const int tx  = tid & 15;
  const int ty  = tid >> 4;
  float acc[2][4] = {{0.f, 0.f, 0.f, 0.f}, {0.f, 0.f, 0.f, 0.f}};

  for (int kt = 0; kt < kDin; kt += 64) {
    __syncthreads();
#pragma unroll
    for (int p = 0; p < 2; ++p) {  // x tile: 32 rows x 64 k (+ fused xf store)
      const int f = tid + p * 256;
      const int row = f >> 4, kq = (f & 15) * 4;
      const float4 v = *(const float4*)(x + (size_t)(i0 + row) * kDin + kt + kq);
      xs[kq + 0][row] = v.x; xs[kq + 1][row] = v.y;
      xs[kq + 2][row] = v.z; xs[kq + 3][row] = v.w;
      us4 h;
      h[0] = f2h(v.x); h[1] = f2h(v.y); h[2] = f2h(v.z); h[3] = f2h(v.w);
      *(us4*)(xf + (size_t)(i0 + row) * kDin + kt + kq) = h;
    }
#pragma unroll
    for (int p = 0; p < 4; ++p) {  // A tile: 64 (t,r) rows x 64 k
      const int f = tid + p * 256;
      const int ar = f >> 4, kq = (f & 15) * 4;
      const int ti = tuner[ar >> 4];
      const float4 v = *(const float4*)(A + ((size_t)ti * kR + (ar & 15)) * kDin + kt + kq);
      as[kq + 0][ar] = v.x; as[kq + 1][ar] = v.y;
      as[kq + 2][ar] = v.z; as[kq + 3][ar] = v.w;
    }
    __syncthreads();
#pragma unroll 4
    for (int k = 0; k < 64; ++k) {
      const float2 xv = *(const float2*)&xs[k][ty * 2];      // b64
      const float4 av = *(const float4*)&as[k][tx * 4];      // b128
      acc[0][0] += xv.x * av.x; acc[0][1] += xv.x * av.y;
      acc[0][2] += xv.x * av.z; acc[0][3] += xv.x * av.w;
      acc[1][0] += xv.y * av.x; acc[1][1] += xv.y * av.y;
      acc[1][2] += xv.y * av.z; acc[1][3] += xv.y * av.w;
    }
  }
#pragma unroll
  for (int ii = 0; ii < 2; ++ii) {
    us4 o;
#pragma unroll
    for (int j = 0; j < 4; ++j) o[j] = f2h(acc[ii][j]);
    *(us4*)(lowb + ((size_t)(tx >> 2) * kM + i0 + ty * 2 + ii) * kR + (tx & 3) * 4) = o;
  }
}

// ---------------------------------------------------------------------------
// Kernel 2: main fp16 MFMA GEMM, tile 128x256 (BK=32), 256 thr = 4 waves as
// 2m x 2n, wave tile 64x128 (acc[8][4]); grid 512; per-t rank-16 epilogue.
// LDS per buffer 24 KB: A [0,8K) 128 rows x 64B; B [8K,24K) 256 rows x 64B.
// Staging: 24 gload_lds/step, 6 per wave (c = 6w+q); counted vmcnt(6).
// Stores: plain f32x4 (retire at L2; writeback overlaps subsequent work).
// ---------------------------------------------------------------------------
__global__ __launch_bounds__(256, 2) void lora_main(
    const unsigned short* __restrict__ xf, const unsigned short* __restrict__ wf,
    const float* __restrict__ bias, const float* __restrict__ Bm,
    const int* __restrict__ tuner, const unsigned short* __restrict__ lowb,
    float* __restrict__ out) {
  __shared__ __align__(16) unsigned char smem[49152];
  const int tid  = threadIdx.x;
  const int lane = tid & 63;
  const int w    = tid >> 6;

  // XCD swizzle (512 blocks, %8==0 -> bijective)
  const int swz = ((int)blockIdx.x & 7) * 64 + ((int)blockIdx.x >> 3);
  const int bm = swz >> 2, bn = swz & 3;
  const size_t i0 = (size_t)bm * 128, j0 = (size_t)bn * 256;
  const int wm = w >> 1, wn = w & 1;   // wave tile: rows wm*64, cols wn*128

  // staging: 24 chunks (1KB = 16 rows x 64B); wave w stages c = 6w..6w+5
  const int chsw = ((lane & 3) ^ ((lane >> 3) & 3)) * 8;
  const unsigned short* gsrc_q[6];
  int ldsoff_q[6];
#pragma unroll
  for (int q = 0; q < 6; ++q) {
    const int c = 6 * w + q;
    const bool isA = c < 8;
    const size_t rowb = (isA ? i0 + c * 16 : j0 + (c - 8) * 16) + (lane >> 2);
    gsrc_q[q] = (isA ? xf : wf) + rowb * kDin + chsw;
    ldsoff_q[q] = c * 1024;   // A: [0,8K); B: [8K,24K)
  }

  f32x4 acc[8][4];   // acc[n][m] = out^T fragments (8 n-frags x 4 m-frags)
#pragma unroll
  for (int n = 0; n < 8; ++n)
#pragma unroll
    for (int m = 0; m < 4; ++m) acc[n][m] = (f32x4){0.f, 0.f, 0.f, 0.f};

  const int kg = lane >> 4;
  const int rl = lane & 15;
  const int csw = kg ^ ((rl >> 1) & 3);
  const int rdA = (wm * 64 + rl) * 64 + csw * 16;           // A region [0,8K)
  const int rdB = 8192 + (wn * 128 + rl) * 64 + csw * 16;   // B region [8K,24K)

  auto compute_step = [&](const unsigned char* B0) {
    f16x8 a[4], b[8];
#pragma unroll
    for (int m = 0; m < 4; ++m) a[m] = *(const f16x8*)(B0 + rdA + m * 1024);
#pragma unroll
    for (int n = 0; n < 8; ++n) b[n] = *(const f16x8*)(B0 + rdB + n * 1024);
    __builtin_amdgcn_s_setprio(1);
#pragma unroll
    for (int n = 0; n < 8; ++n)
#pragma unroll
      for (int m = 0; m < 4; ++m)
        acc[n][m] = mfma_f16(b[n], a[m], acc[n][m]);   // swapped: W as A-operand
    __builtin_amdgcn_s_setprio(0);
  };

  // prologue: stage K-step 0 into buf0 (6 loads/wave)
#pragma unroll
  for (int q = 0; q < 6; ++q)
    gload_lds16(gsrc_q[q], smem + ldsoff_q[q]);

  for (int s = 0; s < 31; ++s) {
    const int p = s & 1;
    {  // prefetch step s+1 into buf p^1 (12 loads/wave outstanding)
      unsigned char* dst = smem + (p ^ 1) * 24576;
      const int ko = (s + 1) * 32;
#pragma unroll
      for (int q = 0; q < 6; ++q)
        gload_lds16(gsrc_q[q] + ko, dst + ldsoff_q[q]);
    }
    asm volatile("s_waitcnt vmcnt(6)" ::: "memory");  // step-s loads landed
    __builtin_amdgcn_s_barrier();
    asm volatile("" ::: "memory");
    compute_step(smem + p * 24576);
    asm volatile("s_waitcnt lgkmcnt(0)" ::: "memory");
    __builtin_amdgcn_s_barrier();
    asm volatile("" ::: "memory");
  }
  asm volatile("s_waitcnt vmcnt(0)" ::: "memory");
  __builtin_amdgcn_s_barrier();
  asm volatile("" ::: "memory");
  compute_step(smem + 24576);   // peeled step 31 reads buf1

  // bias: lane's 4 consecutive out cols = j0 + wn*128 + n*16 + kg*4 + {0..3}
#pragma unroll
  for (int n = 0; n < 8; ++n) {
    const f32x4 bv = *(const f32x4*)(bias + j0 + wn * 128 + n * 16 + kg * 4);
#pragma unroll
    for (int m = 0; m < 4; ++m)
#pragma unroll
      for (int r = 0; r < 4; ++r) acc[n][m][r] += bv[r];
  }

  // Epilogue tiles in buf0 [0,24576): Lt [kg4][128][16B] at [0,8K),
  // Mt [kg4][256][16B] at [8K,24K). Zero kg2-3 pads: Lt [4K,8K), Mt [16K,24K).
  {
    const us8 z = {0, 0, 0, 0, 0, 0, 0, 0};
    if (tid < 128) {
      *(us8*)(smem + 4096 + tid * 32) = z;
      *(us8*)(smem + 4096 + tid * 32 + 16) = z;
    }
    *(us8*)(smem + 16384 + tid * 32) = z;
    *(us8*)(smem + 16384 + tid * 32 + 16) = z;
  }

  for (int t = 0; t < kT; ++t) {
    __syncthreads();  // pads visible / previous t's reads done
    {
      const int row = tid >> 1, half = tid & 1;
      // Lt (low tile, fp16): 128 rows
      const us8 lv = *(const us8*)(lowb + ((size_t)t * kM + i0 + row) * kR + half * 8);
      *(us8*)(smem + half * 2048 + row * 16) = lv;
      // Mt (Bm tile, fp32->fp16): 256 rows, 2 per thread
      const int ti = tuner[t];
#pragma unroll
      for (int rr = 0; rr < 2; ++rr) {
        const int mrow = row + rr * 128;
        const float* bp = Bm + ((size_t)ti * kDout + j0 + mrow) * kR + half * 8;
        const float4 m0 = *(const float4*)bp;
        const float4 m1 = *(const float4*)(bp + 4);
        us8 mv;
        mv[0] = f2h(m0.x); mv[1] = f2h(m0.y); mv[2] = f2h(m0.z); mv[3] = f2h(m0.w);
        mv[4] = f2h(m1.x); mv[5] = f2h(m1.y); mv[6] = f2h(m1.z); mv[7] = f2h(m1.w);
        *(us8*)(smem + 8192 + half * 4096 + mrow * 16) = mv;
      }
    }
    __syncthreads();

    f16x8 lf[4], mf[8];
#pragma unroll
    for (int m = 0; m < 4; ++m)
      lf[m] = *(const f16x8*)(smem + kg * 2048 + (wm * 64 + m * 16 + rl) * 16);
#pragma unroll
    for (int n = 0; n < 8; ++n)
      mf[n] = *(const f16x8*)(smem + 8192 + kg * 4096 + (wn * 128 + n * 16 + rl) * 16);

#pragma unroll
    for (int n = 0; n < 8; ++n)
#pragma unroll
      for (int m = 0; m < 4; ++m) {
        const f32x4 d = mfma_f16(mf[n], lf[m], acc[n][m]);  // = out^T fragment
        const size_t row = (size_t)t * kM + i0 + wm * 64 + m * 16 + rl;
        const int    col = (int)j0 + wn * 128 + n * 16 + kg * 4;
        *(f32x4*)(out + row * kDout + col) = d;   // plain store (L2-retire)
      }
  }
}

// ---------------------------------------------------------------------------
extern "C" void kernel_launch(void* const* d_in, const int* in_sizes, int n_in,
                              void* d_out, int out_size, void* d_ws, size_t ws_size,
                              hipStream_t stream) {
  const float* x    = (const float*)d_in[0];
  const float* W    = (const float*)d_in[1];
  const float* bias = (const float*)d_in[2];
  const float* lA   = (const float*)d_in[3];
  const float* lB   = (const float*)d_in[4];
  const int*   ti   = (const int*)d_in[5];
  float* out = (float*)d_out;

  unsigned char* ws = (unsigned char*)d_ws;
  unsigned short* xfp  = (unsigned short*)(ws + OFF_XF);
  unsigned short* wfp  = (unsigned short*)(ws + OFF_WF);
  unsigned short* lowb = (unsigned short*)(ws + OFF_LOW);

  lora_low<<<kM / 32, 256, 0, stream>>>(x, W, lA, ti, lowb, xfp, wfp);
  lora_main<<<512, 256, 0, stream>>>(xfp, wfp, bias, lB, ti, lowb, out);
}